// Round 3
// baseline (241.271 us; speedup 1.0000x reference)
//
#include <hip/hip_runtime.h>

#define N_DENSE 13
#define N_FIELDS 26
#define PER_FIELD 100000
#define FEATURE_NUM (N_FIELDS * PER_FIELD + N_DENSE)  // 2,600,013
#define K_DIM 16
#define BATCH 4096

// Two 64-lane waves per batch row (wave pair shares a row; 2 rows per 256-thread block).
// lane = g4*16 + k  (g4 in 0..3, k in 0..15); fs = half*4 + g4 in 0..7.
// Each lane gathers V[k, idx(f)] for f = fs, fs+8, fs+16, fs+24 (<26) and
// dense d = fs, fs+8 (<13). Per-k partials (e, sq) are combined across the
// wave pair through LDS BEFORE squaring (e must be the full row sum).
__global__ __launch_bounds__(256) void fm_layer_kernel(
    const float* __restrict__ dense,   // [B, 13]
    const int*   __restrict__ sparse,  // [B, 26]
    const float* __restrict__ w0,      // [1]
    const float* __restrict__ w,       // [FEATURE_NUM]
    const float* __restrict__ V,       // [16, FEATURE_NUM] row-major
    float*       __restrict__ out)     // [B]
{
    const int wave = threadIdx.x >> 6;      // 0..3
    const int lane = threadIdx.x & 63;
    const int rowInBlk = wave >> 1;         // 0..1
    const int half = wave & 1;              // 0..1
    const int b = blockIdx.x * 2 + rowInBlk;

    const int k  = lane & 15;
    const int g4 = lane >> 4;               // 0..3
    const int fs = half * 4 + g4;           // 0..7

    const size_t vrow = (size_t)k * FEATURE_NUM;

    // ---- sparse gather indices: issue index loads first ----
    int gidx[4];
    #pragma unroll
    for (int i = 0; i < 4; ++i) {
        int f = fs + 8 * i;
        gidx[i] = (f < N_FIELDS)
                ? (N_DENSE + f * PER_FIELD + sparse[b * N_FIELDS + f])
                : -1;
    }

    float e = 0.f, sq = 0.f, lin = 0.f;

    // ---- dense part: d = fs, fs+8 (<13) ----
    #pragma unroll
    for (int d = fs; d < N_DENSE; d += 8) {
        float x = dense[b * N_DENSE + d];
        float v = V[vrow + d];
        e  += x * v;
        sq += (x * x) * (v * v);
        if (k == 0) lin += x * w[d];
    }

    // ---- sparse gathers ----
    #pragma unroll
    for (int i = 0; i < 4; ++i) {
        if (gidx[i] >= 0) {
            size_t g = (size_t)gidx[i];
            float v = V[vrow + g];
            e  += v;
            sq += v * v;
            if (k == 0) lin += w[g];
        }
    }

    // ---- intra-wave reduce over the 4 g4 groups (same k) ----
    e  += __shfl_xor(e, 16, 64);
    e  += __shfl_xor(e, 32, 64);
    sq += __shfl_xor(sq, 16, 64);
    sq += __shfl_xor(sq, 32, 64);
    // lin lives on k==0 lanes (0,16,32,48); same reduction totals it on all
    lin += __shfl_xor(lin, 16, 64);
    lin += __shfl_xor(lin, 32, 64);

    // ---- cross-wave (pair) combine through LDS ----
    __shared__ float sE[2][2][16];
    __shared__ float sS[2][2][16];
    __shared__ float sL[2][2];
    if (lane < 16) {
        sE[rowInBlk][half][lane] = e;
        sS[rowInBlk][half][lane] = sq;
    }
    if (lane == 0) sL[rowInBlk][half] = lin;
    __syncthreads();

    if (half == 0 && lane < 16) {
        float eT = sE[rowInBlk][0][lane] + sE[rowInBlk][1][lane];
        float sT = sS[rowInBlk][0][lane] + sS[rowInBlk][1][lane];
        float t = eT * eT - sT;
        // sum t over the 16 k-lanes
        #pragma unroll
        for (int m = 1; m <= 8; m <<= 1) t += __shfl_xor(t, m, 64);
        if (lane == 0) {
            out[b] = w0[0] + sL[rowInBlk][0] + sL[rowInBlk][1] + 0.5f * t;
        }
    }
}

extern "C" void kernel_launch(void* const* d_in, const int* in_sizes, int n_in,
                              void* d_out, int out_size, void* d_ws, size_t ws_size,
                              hipStream_t stream) {
    const float* dense  = (const float*)d_in[0];
    const int*   sparse = (const int*)d_in[1];
    const float* w0     = (const float*)d_in[2];
    const float* w      = (const float*)d_in[3];
    const float* V      = (const float*)d_in[4];
    float* out = (float*)d_out;

    const int blocks = BATCH / 2;  // 2 rows per 256-thread block -> 2048 blocks, 8192 waves
    fm_layer_kernel<<<blocks, 256, 0, stream>>>(dense, sparse, w0, w, V, out);
}